// Round 6
// baseline (557.420 us; speedup 1.0000x reference)
//
#include <hip/hip_runtime.h>
#include <hip/hip_bf16.h>
#include <hip/hip_cooperative_groups.h>

namespace cg = cooperative_groups;

// GCN 2-layer: h1' = relu(S·(x@w1) + b1); out = S·(h1'@w2) + b2
// Single-pass bucket multisplit -> exact CSR by dst; gather = 2 nodes/wave,
// 16 lanes x ushort4/edge, 64-rec preload + shfl broadcast; bf16 MFMA gemms.
// Post-sort chain runs as ONE cooperative kernel (grid.sync between phases)
// to remove ~3 launch gaps (~9us each).
// N=100000, E=1600000, IN=128, HID=64, OUT=64.
//
// Perf journal:
//  R1 2862; R2 633; R3 466; R4 1587 REG; R5 326; R6 262; R7 276 REG
//  R8 246.8: broadcast gather, 2 nodes/wave, 1-pass sort
//  R9 232.6 BEST: fused pass1+gemm1 overlap, pass2@1024, unroll 4
//  R10 235.6 REG: 4blk/CU occupancy play -- occupancy NOT the limiter
//  R11 247.8 REG: gemm2 fused into gather1 end (+12us tax) + reg-staged p1
//  R12 255.1 REG: issue-phase gather neutral (53us); MLP not the limiter
//  R13 245.3 REG: aggregate-then-transform gather2mm +12us tax again,
//     +70MB write-allocate; K-split gemm1 staging ~+8us hidden REG.
//     Gather now triple-confirmed pinned ~52us (MSHR-bound random lines).
//  R14 (this): R9 bodies restored verbatim (full-A gemm1, separate gemm2,
//     R9 gathers); shfl-scan kept in pass1 (HW-verified, fewer barriers);
//     {pass2,gather1,gemm2,gather2} merged into ONE cooperative kernel,
//     grid=768x256, launch_bounds(256,4) guarantees residency.

#define N_NODES 100000
#define N_EDGES 1600000
#define NB1     391     // coarse buckets of 256 dst nodes (dst>>8)
#define T1      4096    // pass-1 tile (edges per block)
#define NT1     391     // ceil(E/T1)
#define CAP1    4706    // per-bucket slack: mean 4092 + 9.6 sigma
#define GB1     782     // fused-kernel gemm blocks: ceil(N/128)
#define RESTB   768     // cooperative grid (3/CU; >=4/CU residency bound)

typedef unsigned short ushort_t;
typedef unsigned int uint_t;
typedef __attribute__((ext_vector_type(8))) short bf16x8;
typedef __attribute__((ext_vector_type(4))) float floatx4;
typedef __attribute__((ext_vector_type(8))) ushort_t ushort8v;

static __device__ __forceinline__ float bf2f(ushort_t h) {
    return __uint_as_float(((uint_t)h) << 16);
}
static __device__ __forceinline__ ushort_t f2bf(float f) {
    uint_t u = __float_as_uint(f);
    u = (u + 0x7FFF + ((u >> 16) & 1)) >> 16;   // RNE
    return (ushort_t)u;
}

// ---------------------------------------------------------------------------
// gcursor[b] = b * CAP1  (bucket window bases)
// ---------------------------------------------------------------------------
__global__ __launch_bounds__(512) void k_init(int* __restrict__ gcursor)
{
    int t = threadIdx.x;
    if (t < NB1) gcursor[t] = t * CAP1;
}

// ---------------------------------------------------------------------------
// FUSED: blocks [0,NT1) run sort pass 1; blocks [NT1,NT1+GB1) run GEMM1.
// Data-independent roles overlap on the CU array. LDS 52224 -> 3 blk/CU.
//
// Pass 1: LDS histogram of 391 buckets; shfl wave-scan (3 barriers);
// one global atomicAdd per (tile,bucket) reserves output space; LDS
// binning; stream out bucket-grouped runs. rec.x=(dst&255)<<17|src.
//
// GEMM1 (R9 form, 128 rows/block, 8 waves): Y[bf16,Nx64] =
// bf16(X[f32,Nx128]) @ bf16(W[128x64]). Full-K A stage (34.8KB, ONE
// staging phase -- K-split variant measured ~+8us, reverted).
// ---------------------------------------------------------------------------
__global__ __launch_bounds__(512) void k_p1g1(
    const int* __restrict__ src, const int* __restrict__ dst,
    const float* __restrict__ ew, int* __restrict__ gcursor,
    int2* __restrict__ recs1, int E,
    const float* __restrict__ X, const float* __restrict__ W,
    ushort_t* __restrict__ Y, int N)
{
    __shared__ __align__(16) char smem[52224];
    const int tid = threadIdx.x;

    if (blockIdx.x < NT1) {
        // ---------------- sort pass 1 ----------------
        int* cnt     = (int*)smem;                 // [NB1]
        int* start   = cnt + NB1;
        int* cursor  = start + NB1;
        int* gb      = cursor + NB1;               // ends 6256
        int* wsum    = (int*)(smem + 6256);        // [8]
        int* wexc    = wsum + 8;                   // [8], ends 6320
        int2* stg    = (int2*)(smem + 6336);       // [T1], ends 39104
        ushort_t* sb = (ushort_t*)(smem + 39104);  // [T1], ends 47296
        const int t = tid, b = blockIdx.x;
        const int lane = t & 63, wv = t >> 6;

        if (t < NB1) cnt[t] = 0;
        __syncthreads();
        const int e0 = b * T1;
        const int e1 = min(E, e0 + T1);
        for (int e = e0 + t; e < e1; e += 512)
            atomicAdd(&cnt[dst[e] >> 8], 1);
        __syncthreads();

        // shfl-based scan of cnt[0..NB1): wave-inclusive + 8-wide cross-wave
        const int v = (t < NB1) ? cnt[t] : 0;
        int x = v;
        #pragma unroll
        for (int off = 1; off < 64; off <<= 1) {
            int y = __shfl_up(x, off);
            if (lane >= off) x += y;
        }
        if (lane == 63) wsum[wv] = x;
        __syncthreads();
        if (t < 8) {
            int w  = wsum[t];
            int xx = w;
            #pragma unroll
            for (int off = 1; off < 8; off <<= 1) {
                int y = __shfl_up(xx, off);
                if (t >= off) xx += y;
            }
            wexc[t] = xx - w;
        }
        __syncthreads();
        if (t < NB1) {
            int st = x + wexc[wv] - v;             // exclusive prefix
            start[t]  = st;
            cursor[t] = st;
            gb[t]     = atomicAdd(&gcursor[t], v); // device-scope reservation
        }
        __syncthreads();

        for (int e = e0 + t; e < e1; e += 512) {
            int d  = dst[e];
            int bk = d >> 8;
            int p  = atomicAdd(&cursor[bk], 1);
            int2 r;
            r.x = ((d & 255) << 17) | src[e];
            r.y = __float_as_int(ew[e]);
            stg[p] = r;
            sb[p]  = (ushort_t)bk;
        }
        __syncthreads();
        const int n = e1 - e0;
        for (int i = t; i < n; i += 512) {
            int bk = sb[i];
            recs1[gb[bk] + (i - start[bk])] = stg[i];
        }
    } else {
        // ---------------- GEMM1 (R9 form), 128 rows ----------------
        ushort_t* sA = (ushort_t*)smem;             // 128 x 136
        ushort_t* sB = (ushort_t*)(smem + 34816);   // 64 x 136 (B^T)
        const int b    = blockIdx.x - NT1;
        const int row0 = b * 128;

        for (int i = tid; i < 128 * 32; i += 512) {    // A: 128 rows x 32 f4
            int r = i >> 5, c4 = (i & 31) * 4;
            int rg = row0 + r; if (rg > N - 1) rg = N - 1;
            float4 v = *(const float4*)(X + (size_t)rg * 128 + c4);
            ushort4 pk = make_ushort4(f2bf(v.x), f2bf(v.y), f2bf(v.z), f2bf(v.w));
            *(ushort4*)(sA + r * 136 + c4) = pk;
        }
        for (int i = tid; i < 128 * 16; i += 512) {    // B: 128 rows x 16 f4
            int k = i >> 4, n4 = (i & 15) * 4;
            float4 v = *(const float4*)(W + (size_t)k * 64 + n4);
            sB[(n4 + 0) * 136 + k] = f2bf(v.x);
            sB[(n4 + 1) * 136 + k] = f2bf(v.y);
            sB[(n4 + 2) * 136 + k] = f2bf(v.z);
            sB[(n4 + 3) * 136 + k] = f2bf(v.w);
        }
        __syncthreads();

        const int wid = tid >> 6, lane = tid & 63;     // wid 0..7 -> 128 rows
        const int m = lane & 15, quad = lane >> 4;
        floatx4 acc[4] = {};

        #pragma unroll
        for (int ks = 0; ks < 4; ++ks) {
            bf16x8 a = *(const bf16x8*)(sA + (wid * 16 + m) * 136 + ks * 32 + quad * 8);
            #pragma unroll
            for (int nt = 0; nt < 4; ++nt) {
                bf16x8 bfr = *(const bf16x8*)(sB + (nt * 16 + m) * 136 + ks * 32 + quad * 8);
                acc[nt] = __builtin_amdgcn_mfma_f32_16x16x32_bf16(a, bfr, acc[nt], 0, 0, 0);
            }
        }
        __syncthreads();                    // all sA reads done
        #pragma unroll
        for (int nt = 0; nt < 4; ++nt)
            #pragma unroll
            for (int r = 0; r < 4; ++r)
                sA[(wid * 16 + quad * 4 + r) * 72 + nt * 16 + m] = f2bf(acc[nt][r]);
        __syncthreads();
        for (int i = tid; i < 128 * 8; i += 512) {     // coalesced C store
            int rr = i >> 3, c8 = (i & 7) * 8;
            int rg = row0 + rr;
            if (rg < N)
                *(ushort8v*)(Y + (size_t)rg * 64 + c8) =
                    *(const ushort8v*)(sA + rr * 72 + c8);
        }
    }
}

// ---------------------------------------------------------------------------
// Gather-reduce item (R9 body): one wave, 2 nodes. 64-rec preload + shfl
// broadcast; group g=lane>>4 handles edge jj+g; 16 lanes x ushort4/edge;
// unroll 4 (8 H-loads in flight). Barrier-free.
// ---------------------------------------------------------------------------
template<bool RELU, bool OUT_BF16>
static __device__ __forceinline__ void gather_item(
    int i, int wid, int lane,
    const ushort_t* __restrict__ H, const int2* __restrict__ recs,
    const int2* __restrict__ nodeinfo, const float* __restrict__ bias,
    void* __restrict__ out)
{
    const int n0 = (i * 4 + wid) * 2;
    const int n1 = n0 + 1;

    const int2 niA = nodeinfo[n0];
    const int2 niB = nodeinfo[n1];
    int baseA = niA.x; const int endA = niA.x + niA.y;
    int baseB = niB.x; const int endB = niB.x + niB.y;

    const int g  = lane >> 4;           // edge slot in round
    const int c4 = (lane & 15) * 4;     // channel base

    float a0 = 0.f, a1 = 0.f, a2 = 0.f, a3 = 0.f;
    float b0 = 0.f, b1 = 0.f, b2 = 0.f, b3 = 0.f;

    while (baseA < endA || baseB < endB) {
        int mA = endA - baseA; if (mA > 64) mA = 64;
        int mB = endB - baseB; if (mB > 64) mB = 64;
        int2 rA = (mA > 0) ? recs[baseA + (lane < mA ? lane : mA - 1)]
                           : make_int2(0, 0);
        int2 rB = (mB > 0) ? recs[baseB + (lane < mB ? lane : mB - 1)]
                           : make_int2(0, 0);
        float wAf = __int_as_float(rA.y);
        float wBf = __int_as_float(rB.y);
        int mm = mA > mB ? mA : mB;
        #pragma unroll 4
        for (int jj = 0; jj < mm; jj += 4) {
            int idx = jj + g;
            int   sA = __shfl(rA.x, idx);
            float wA = __shfl(wAf, idx);
            int   sB = __shfl(rB.x, idx);
            float wB = __shfl(wBf, idx);
            if (idx >= mA) wA = 0.f;
            if (idx >= mB) wB = 0.f;
            ushort4 hA = *(const ushort4*)(H + (size_t)sA * 64 + c4);
            ushort4 hB = *(const ushort4*)(H + (size_t)sB * 64 + c4);
            a0 = fmaf(wA, bf2f(hA.x), a0);
            a1 = fmaf(wA, bf2f(hA.y), a1);
            a2 = fmaf(wA, bf2f(hA.z), a2);
            a3 = fmaf(wA, bf2f(hA.w), a3);
            b0 = fmaf(wB, bf2f(hB.x), b0);
            b1 = fmaf(wB, bf2f(hB.y), b1);
            b2 = fmaf(wB, bf2f(hB.z), b2);
            b3 = fmaf(wB, bf2f(hB.w), b3);
        }
        baseA += 64;
        baseB += 64;
    }
    a0 += __shfl_down(a0, 32); a1 += __shfl_down(a1, 32);
    a2 += __shfl_down(a2, 32); a3 += __shfl_down(a3, 32);
    b0 += __shfl_down(b0, 32); b1 += __shfl_down(b1, 32);
    b2 += __shfl_down(b2, 32); b3 += __shfl_down(b3, 32);
    a0 += __shfl_down(a0, 16); a1 += __shfl_down(a1, 16);
    a2 += __shfl_down(a2, 16); a3 += __shfl_down(a3, 16);
    b0 += __shfl_down(b0, 16); b1 += __shfl_down(b1, 16);
    b2 += __shfl_down(b2, 16); b3 += __shfl_down(b3, 16);

    if (lane < 16) {
        float4 bv = *(const float4*)(bias + c4);
        float vA0 = a0 + bv.x, vA1 = a1 + bv.y, vA2 = a2 + bv.z, vA3 = a3 + bv.w;
        float vB0 = b0 + bv.x, vB1 = b1 + bv.y, vB2 = b2 + bv.z, vB3 = b3 + bv.w;
        if (RELU) {
            vA0 = fmaxf(vA0, 0.f); vA1 = fmaxf(vA1, 0.f);
            vA2 = fmaxf(vA2, 0.f); vA3 = fmaxf(vA3, 0.f);
            vB0 = fmaxf(vB0, 0.f); vB1 = fmaxf(vB1, 0.f);
            vB2 = fmaxf(vB2, 0.f); vB3 = fmaxf(vB3, 0.f);
        }
        if (OUT_BF16) {
            *(ushort4*)((ushort_t*)out + (size_t)n0 * 64 + c4) =
                make_ushort4(f2bf(vA0), f2bf(vA1), f2bf(vA2), f2bf(vA3));
            *(ushort4*)((ushort_t*)out + (size_t)n1 * 64 + c4) =
                make_ushort4(f2bf(vB0), f2bf(vB1), f2bf(vB2), f2bf(vB3));
        } else {
            *(float4*)((float*)out + (size_t)n0 * 64 + c4) =
                make_float4(vA0, vA1, vA2, vA3);
            *(float4*)((float*)out + (size_t)n1 * 64 + c4) =
                make_float4(vB0, vB1, vB2, vB3);
        }
    }
}

// ---------------------------------------------------------------------------
// Cooperative post-sort chain: pass2 -> gather1 -> gemm2 -> gather2,
// separated by grid.sync(). Phase bodies are the R9 kernel bodies wrapped
// in grid-stride loops; numerics unchanged. 768 blocks x 256 threads;
// launch_bounds(256,4) caps VGPR at 128 -> >=4 blk/CU resident (LDS
// 18.4KB -> 8/CU), so 768 blocks are guaranteed co-resident.
// ---------------------------------------------------------------------------
__global__ __launch_bounds__(256, 4) void k_rest(
    const int2* __restrict__ recs1, const int* __restrict__ gcursor,
    int2* __restrict__ recs2, int2* __restrict__ ninfo,
    ushort_t* __restrict__ bufA,          // in: h1; overwritten with h2
    const float* __restrict__ b1, ushort_t* __restrict__ bufB,   // h1'
    const float* __restrict__ w2, const float* __restrict__ b2,
    float* __restrict__ out, int N)
{
    cg::grid_group grid = cg::this_grid();
    __shared__ __align__(16) char smem[18432];
    const int tid  = threadIdx.x;
    const int wid  = tid >> 6;
    const int lane = tid & 63;

    // ================= phase A: pass2 (exact CSR) =================
    {
        int* cnt    = (int*)smem;          // [256]
        int* cursor = cnt + 256;           // [256]
        int* wsum   = cursor + 256;        // [4]
        int* wexc   = wsum + 8;            // [4]
        const int t = tid;
        for (int b = blockIdx.x; b < NB1; b += gridDim.x) {
            const int lo = b * CAP1;
            const int hi = gcursor[b];
            cnt[t] = 0;
            __syncthreads();
            for (int j = lo + t; j < hi; j += 256)
                atomicAdd(&cnt[((uint_t)recs1[j].x) >> 17], 1);
            __syncthreads();
            const int v = cnt[t];
            int x = v;                      // wave-inclusive scan
            #pragma unroll
            for (int off = 1; off < 64; off <<= 1) {
                int y = __shfl_up(x, off);
                if (lane >= off) x += y;
            }
            if (lane == 63) wsum[wid] = x;
            __syncthreads();
            if (t < 4) {
                int w  = wsum[t];
                int xx = w;
                #pragma unroll
                for (int off = 1; off < 4; off <<= 1) {
                    int y = __shfl_up(xx, off);
                    if (t >= off) xx += y;
                }
                wexc[t] = xx - w;
            }
            __syncthreads();
            const int stl = x + wexc[wid] - v;   // exclusive prefix
            cursor[t] = stl;
            const int ng = b * 256 + t;
            if (ng < N) {
                int2 ni; ni.x = lo + stl; ni.y = v;
                ninfo[ng] = ni;
            }
            __syncthreads();
            for (int j = lo + t; j < hi; j += 256) {
                int2 r = recs1[j];
                int dl = ((uint_t)r.x) >> 17;
                int p  = atomicAdd(&cursor[dl], 1);
                int2 o;
                o.x = r.x & 0x1FFFF;
                o.y = r.y;
                recs2[lo + p] = o;
            }
            __syncthreads();               // smem reuse across buckets
        }
    }
    grid.sync();

    // ================= phase B: gather layer 1 =================
    for (int i = blockIdx.x; i < N_NODES / 8; i += gridDim.x)
        gather_item<true, true>(i, wid, lane, bufA, recs2, ninfo, b1, bufB);
    grid.sync();

    // ================= phase C: gemm2  h2 = h1' @ W2 =================
    {
        ushort_t* sA = (ushort_t*)smem;            // 64 x 72 (A / C stage)
        ushort_t* sB = (ushort_t*)(smem + 9216);   // 64 x 72 (B^T)
        const int m = lane & 15, quad = lane >> 4;
        for (int it = blockIdx.x; it < (N_NODES + 63) / 64; it += gridDim.x) {
            const int row0 = it * 64;
            for (int i = tid; i < 64 * 16; i += 256) {     // A rows
                int r = i >> 4, c4 = (i & 15) * 4;
                int rg = row0 + r; if (rg > N - 1) rg = N - 1;
                *(ushort4*)(sA + r * 72 + c4) =
                    *(const ushort4*)(bufB + (size_t)rg * 64 + c4);
            }
            for (int i = tid; i < 64 * 16; i += 256) {     // B^T
                int k = i >> 4, n4 = (i & 15) * 4;
                float4 v = *(const float4*)(w2 + (size_t)k * 64 + n4);
                sB[(n4 + 0) * 72 + k] = f2bf(v.x);
                sB[(n4 + 1) * 72 + k] = f2bf(v.y);
                sB[(n4 + 2) * 72 + k] = f2bf(v.z);
                sB[(n4 + 3) * 72 + k] = f2bf(v.w);
            }
            __syncthreads();
            floatx4 acc[4] = {};
            #pragma unroll
            for (int ks = 0; ks < 2; ++ks) {
                bf16x8 a = *(const bf16x8*)(sA + (wid * 16 + m) * 72 + ks * 32 + quad * 8);
                #pragma unroll
                for (int nt = 0; nt < 4; ++nt) {
                    bf16x8 bfr = *(const bf16x8*)(sB + (nt * 16 + m) * 72 + ks * 32 + quad * 8);
                    acc[nt] = __builtin_amdgcn_mfma_f32_16x16x32_bf16(a, bfr, acc[nt], 0, 0, 0);
                }
            }
            __syncthreads();
            #pragma unroll
            for (int nt = 0; nt < 4; ++nt)
                #pragma unroll
                for (int r = 0; r < 4; ++r)
                    sA[(wid * 16 + quad * 4 + r) * 72 + nt * 16 + m] = f2bf(acc[nt][r]);
            __syncthreads();
            for (int i = tid; i < 64 * 8; i += 256) {
                int rr = i >> 3, c8 = (i & 7) * 8;
                int rg = row0 + rr;
                if (rg < N)
                    *(ushort8v*)(bufA + (size_t)rg * 64 + c8) =
                        *(const ushort8v*)(sA + rr * 72 + c8);
            }
            __syncthreads();               // stores read sA; next it rewrites
        }
    }
    grid.sync();

    // ================= phase D: gather layer 2 =================
    for (int i = blockIdx.x; i < N_NODES / 8; i += gridDim.x)
        gather_item<false, false>(i, wid, lane, bufA, recs2, ninfo, b2, out);
}

// ---------------------------------------------------------------------------
extern "C" void kernel_launch(void* const* d_in, const int* in_sizes, int n_in,
                              void* d_out, int out_size, void* d_ws, size_t ws_size,
                              hipStream_t stream) {
    const float* x   = (const float*)d_in[0];
    const int*   ei  = (const int*)  d_in[1];
    const float* ew  = (const float*)d_in[2];
    const float* w1  = (const float*)d_in[3];
    const float* b1  = (const float*)d_in[4];
    const float* w2  = (const float*)d_in[5];
    const float* b2  = (const float*)d_in[6];
    float* out = (float*)d_out;

    int N = N_NODES, E = N_EDGES;
    const int* src = ei;
    const int* dst = ei + E;

    char* p = (char*)d_ws;
    ushort_t* bufA   = (ushort_t*)p;  p += (size_t)N_NODES * 64 * 2;   // 12.8MB: h1 / h2
    int2*     recs2  = (int2*)p;      p += (size_t)NB1 * CAP1 * 8;     // 14.7MB: exact CSR
    // recs1 (pass-1 output) aliases bufB: recs1 dead after phase A (pass2),
    // which grid.sync-precedes phase B's writes to bufB.
    int2*     recs1  = (int2*)p;
    ushort_t* bufB   = (ushort_t*)p;  p += (size_t)NB1 * CAP1 * 8;     // 14.7MB: h1'
    int*      gcur   = (int*)p;       p += 2048;
    int2*     ninfo  = (int2*)p;      p += (size_t)N_NODES * 8;        // 0.8MB

    // ---- sort pass1 + GEMM1 fused (independent; overlap on CU array)
    k_init <<<1, 512, 0, stream>>>(gcur);
    k_p1g1 <<<NT1 + GB1, 512, 0, stream>>>(src, dst, ew, gcur, recs1, E,
                                           x, w1, bufA, N);

    // ---- cooperative post-sort chain (pass2 -> g1 -> gemm2 -> g2)
    void* args[] = {
        (void*)&recs1, (void*)&gcur, (void*)&recs2, (void*)&ninfo,
        (void*)&bufA,  (void*)&b1,   (void*)&bufB,
        (void*)&w2,    (void*)&b2,   (void*)&out,   (void*)&N
    };
    hipLaunchCooperativeKernel((void*)k_rest, dim3(RESTB), dim3(256),
                               args, 0, stream);
}

// Round 7
// 243.219 us; speedup vs baseline: 2.2918x; 2.2918x over previous
//
#include <hip/hip_runtime.h>
#include <hip/hip_bf16.h>

// GCN 2-layer: h1' = relu(S·(x@w1) + b1); out = S·(h1'@w2) + b2
//            = (S·h1')@w2 + b2 for layer 2 (linearity)
// Single-pass bucket multisplit -> exact CSR by dst; gather = 2 nodes/wave,
// 16 lanes x ushort4/edge, 64-rec preload + shfl broadcast; bf16 MFMA.
// N=100000, E=1600000, IN=128, HID=64, OUT=64.
//
// Perf journal:
//  R1 2862; R2 633; R3 466; R4 1587 REG; R5 326; R6 262; R7 276 REG
//  R8 246.8; R9 232.6 BEST (fused p1+gemm1, pass2@1024, unroll4)
//  R10 235.6 REG: occupancy play -- occupancy not the limiter
//  R11 247.8 REG: gather1-end fusion, block barrier coupled waves
//  R12 255.1 REG: issue-phase gather neutral; MLP not the limiter
//  R13 245.3 REG: gather2 fusion tax = scattered scalar f32 stores
//     (+70MB write-allocate fetch), NOT the MFMA epilogue; numerics PASS
//  R14 557.4 REG: cooperative merge strangled gather TLP (768 blocks);
//     gather needs max wave count -- cooperative dead end
//  R15 (this): R9 source verbatim + ONE change: k_gemm2 deleted, gather2
//     aggregates h1' then applies W2 in-wave (R13 numerics) with FIXED
//     stores: wave-private strip, wave_barrier only, coalesced float4
//     row stores. -1 kernel, -1 gap, -25.6MB round trip.

#define N_NODES 100000
#define N_EDGES 1600000
#define NB1     391     // coarse buckets of 256 dst nodes (dst>>8)
#define T1      4096    // pass-1 tile (edges per block)
#define NT1     391     // ceil(E/T1)
#define CAP1    4706    // per-bucket slack: mean 4092 + 9.6 sigma
#define GB1     782     // fused-kernel gemm blocks: ceil(N/128)

typedef unsigned short ushort_t;
typedef unsigned int uint_t;
typedef __attribute__((ext_vector_type(8))) short bf16x8;
typedef __attribute__((ext_vector_type(4))) float floatx4;
typedef __attribute__((ext_vector_type(8))) ushort_t ushort8v;

static __device__ __forceinline__ float bf2f(ushort_t h) {
    return __uint_as_float(((uint_t)h) << 16);
}
static __device__ __forceinline__ ushort_t f2bf(float f) {
    uint_t u = __float_as_uint(f);
    u = (u + 0x7FFF + ((u >> 16) & 1)) >> 16;   // RNE
    return (ushort_t)u;
}

// ---------------------------------------------------------------------------
// gcursor[b] = b * CAP1  (bucket window bases)
// ---------------------------------------------------------------------------
__global__ __launch_bounds__(512) void k_init(int* __restrict__ gcursor)
{
    int t = threadIdx.x;
    if (t < NB1) gcursor[t] = t * CAP1;
}

// ---------------------------------------------------------------------------
// FUSED (R9 verbatim): blocks [0,NT1) sort pass 1; [NT1,NT1+GB1) GEMM1.
// ---------------------------------------------------------------------------
__global__ __launch_bounds__(512) void k_p1g1(
    const int* __restrict__ src, const int* __restrict__ dst,
    const float* __restrict__ ew, int* __restrict__ gcursor,
    int2* __restrict__ recs1, int E,
    const float* __restrict__ X, const float* __restrict__ W,
    ushort_t* __restrict__ Y, int N)
{
    __shared__ __align__(16) char smem[52224];
    const int tid = threadIdx.x;

    if (blockIdx.x < NT1) {
        // ---------------- sort pass 1 ----------------
        int* cnt     = (int*)smem;             // [NB1]
        int* start   = cnt + NB1;
        int* cursor  = start + NB1;
        int* gb      = cursor + NB1;
        int* s       = (int*)(smem + 6256);    // [512]
        int2* stg    = (int2*)(smem + 8304);   // [T1]
        ushort_t* sb = (ushort_t*)(smem + 41072); // [T1]
        const int t = tid, b = blockIdx.x;

        if (t < NB1) cnt[t] = 0;
        __syncthreads();
        const int e0 = b * T1;
        const int e1 = min(E, e0 + T1);
        for (int e = e0 + t; e < e1; e += 512)
            atomicAdd(&cnt[dst[e] >> 8], 1);
        __syncthreads();
        const int v = (t < NB1) ? cnt[t] : 0;
        s[t] = v;
        #pragma unroll
        for (int off = 1; off < 512; off <<= 1) {
            __syncthreads();
            int a = (t >= off) ? s[t - off] : 0;
            __syncthreads();
            s[t] += a;
        }
        __syncthreads();
        if (t < NB1) {
            int st = s[t] - v;
            start[t]  = st;
            cursor[t] = st;
            gb[t]     = atomicAdd(&gcursor[t], v);   // device-scope reservation
        }
        __syncthreads();
        for (int e = e0 + t; e < e1; e += 512) {
            int d  = dst[e];
            int bk = d >> 8;
            int p  = atomicAdd(&cursor[bk], 1);
            int2 r;
            r.x = ((d & 255) << 17) | src[e];
            r.y = __float_as_int(ew[e]);
            stg[p] = r;
            sb[p]  = (ushort_t)bk;
        }
        __syncthreads();
        const int n = e1 - e0;
        for (int i = t; i < n; i += 512) {
            int bk = sb[i];
            recs1[gb[bk] + (i - start[bk])] = stg[i];
        }
    } else {
        // ---------------- GEMM1, 128 rows ----------------
        ushort_t* sA = (ushort_t*)smem;             // 128 x 136
        ushort_t* sB = (ushort_t*)(smem + 34816);   // 64 x 136 (transposed)
        const int b    = blockIdx.x - NT1;
        const int row0 = b * 128;

        for (int i = tid; i < 128 * 32; i += 512) {    // A: 128 rows x 32 f4
            int r = i >> 5, c4 = (i & 31) * 4;
            int rg = row0 + r; if (rg > N - 1) rg = N - 1;
            float4 v = *(const float4*)(X + (size_t)rg * 128 + c4);
            ushort4 pk = make_ushort4(f2bf(v.x), f2bf(v.y), f2bf(v.z), f2bf(v.w));
            *(ushort4*)(sA + r * 136 + c4) = pk;
        }
        for (int i = tid; i < 128 * 16; i += 512) {    // B: 128 rows x 16 f4
            int k = i >> 4, n4 = (i & 15) * 4;
            float4 v = *(const float4*)(W + (size_t)k * 64 + n4);
            sB[(n4 + 0) * 136 + k] = f2bf(v.x);
            sB[(n4 + 1) * 136 + k] = f2bf(v.y);
            sB[(n4 + 2) * 136 + k] = f2bf(v.z);
            sB[(n4 + 3) * 136 + k] = f2bf(v.w);
        }
        __syncthreads();

        const int wid = tid >> 6, lane = tid & 63;     // wid 0..7 -> 128 rows
        const int m = lane & 15, quad = lane >> 4;
        floatx4 acc[4] = {};

        #pragma unroll
        for (int ks = 0; ks < 4; ++ks) {
            bf16x8 a = *(const bf16x8*)(sA + (wid * 16 + m) * 136 + ks * 32 + quad * 8);
            #pragma unroll
            for (int nt = 0; nt < 4; ++nt) {
                bf16x8 bfr = *(const bf16x8*)(sB + (nt * 16 + m) * 136 + ks * 32 + quad * 8);
                acc[nt] = __builtin_amdgcn_mfma_f32_16x16x32_bf16(a, bfr, acc[nt], 0, 0, 0);
            }
        }
        __syncthreads();                    // all sA reads done
        #pragma unroll
        for (int nt = 0; nt < 4; ++nt)
            #pragma unroll
            for (int r = 0; r < 4; ++r)
                sA[(wid * 16 + quad * 4 + r) * 72 + nt * 16 + m] = f2bf(acc[nt][r]);
        __syncthreads();
        for (int i = tid; i < 128 * 8; i += 512) {     // coalesced C store
            int rr = i >> 3, c8 = (i & 7) * 8;
            int rg = row0 + rr;
            if (rg < N)
                *(ushort8v*)(Y + (size_t)rg * 64 + c8) =
                    *(const ushort8v*)(sA + rr * 72 + c8);
        }
    }
}

// ---------------------------------------------------------------------------
// Pass 2 (R9 verbatim): one block per coarse bucket -> exact per-node CSR.
// ---------------------------------------------------------------------------
__global__ __launch_bounds__(1024) void k_pass2(
    const int2* __restrict__ recs1, const int* __restrict__ gcursor,
    int2* __restrict__ recs2, int2* __restrict__ nodeinfo, int N)
{
    __shared__ int cnt[256];
    __shared__ int s[256];
    __shared__ int cursor[256];
    const int t = threadIdx.x, b = blockIdx.x;
    const int lo = b * CAP1;
    const int hi = gcursor[b];

    if (t < 256) cnt[t] = 0;
    __syncthreads();
    for (int j = lo + t; j < hi; j += 1024)
        atomicAdd(&cnt[((uint_t)recs1[j].x) >> 17], 1);
    __syncthreads();
    const int v = (t < 256) ? cnt[t] : 0;
    if (t < 256) s[t] = v;
    #pragma unroll
    for (int off = 1; off < 256; off <<= 1) {
        __syncthreads();
        int a = (t >= off && t < 256) ? s[t - off] : 0;
        __syncthreads();
        if (t < 256) s[t] += a;
    }
    __syncthreads();
    if (t < 256) {
        const int stl = s[t] - v;
        cursor[t] = stl;
        const int ng = b * 256 + t;
        if (ng < N) {
            int2 ni; ni.x = lo + stl; ni.y = v;
            nodeinfo[ng] = ni;
        }
    }
    __syncthreads();
    for (int j = lo + t; j < hi; j += 1024) {
        int2 r = recs1[j];
        int dl = ((uint_t)r.x) >> 17;
        int p  = atomicAdd(&cursor[dl], 1);
        int2 o;
        o.x = r.x & 0x1FFFF;
        o.y = r.y;
        recs2[lo + p] = o;
    }
}

// ---------------------------------------------------------------------------
// Gather-reduce layer 1 (R9 verbatim): 2 nodes/wave, 64-rec preload + shfl
// broadcast, 16 lanes x ushort4/edge, unroll 4. relu+bias, bf16 out.
// ---------------------------------------------------------------------------
__global__ __launch_bounds__(256) void k_gather1(
    const ushort_t* __restrict__ H, const int2* __restrict__ recs,
    const int2* __restrict__ nodeinfo, const float* __restrict__ bias,
    ushort_t* __restrict__ out)
{
    const int wid  = threadIdx.x >> 6;
    const int lane = threadIdx.x & 63;
    const int n0   = (blockIdx.x * 4 + wid) * 2;   // grid = N/8 exactly
    const int n1   = n0 + 1;

    const int2 niA = nodeinfo[n0];
    const int2 niB = nodeinfo[n1];
    int baseA = niA.x; const int endA = niA.x + niA.y;
    int baseB = niB.x; const int endB = niB.x + niB.y;

    const int g  = lane >> 4;           // edge slot in round
    const int c4 = (lane & 15) * 4;     // channel base

    float a0 = 0.f, a1 = 0.f, a2 = 0.f, a3 = 0.f;
    float b0 = 0.f, b1 = 0.f, b2 = 0.f, b3 = 0.f;

    while (baseA < endA || baseB < endB) {
        int mA = endA - baseA; if (mA > 64) mA = 64;
        int mB = endB - baseB; if (mB > 64) mB = 64;
        int2 rA = (mA > 0) ? recs[baseA + (lane < mA ? lane : mA - 1)]
                           : make_int2(0, 0);
        int2 rB = (mB > 0) ? recs[baseB + (lane < mB ? lane : mB - 1)]
                           : make_int2(0, 0);
        float wAf = __int_as_float(rA.y);
        float wBf = __int_as_float(rB.y);
        int mm = mA > mB ? mA : mB;
        #pragma unroll 4
        for (int jj = 0; jj < mm; jj += 4) {
            int idx = jj + g;
            int   sA = __shfl(rA.x, idx);
            float wA = __shfl(wAf, idx);
            int   sB = __shfl(rB.x, idx);
            float wB = __shfl(wBf, idx);
            if (idx >= mA) wA = 0.f;
            if (idx >= mB) wB = 0.f;
            ushort4 hA = *(const ushort4*)(H + (size_t)sA * 64 + c4);
            ushort4 hB = *(const ushort4*)(H + (size_t)sB * 64 + c4);
            a0 = fmaf(wA, bf2f(hA.x), a0);
            a1 = fmaf(wA, bf2f(hA.y), a1);
            a2 = fmaf(wA, bf2f(hA.z), a2);
            a3 = fmaf(wA, bf2f(hA.w), a3);
            b0 = fmaf(wB, bf2f(hB.x), b0);
            b1 = fmaf(wB, bf2f(hB.y), b1);
            b2 = fmaf(wB, bf2f(hB.z), b2);
            b3 = fmaf(wB, bf2f(hB.w), b3);
        }
        baseA += 64;
        baseB += 64;
    }
    a0 += __shfl_down(a0, 32); a1 += __shfl_down(a1, 32);
    a2 += __shfl_down(a2, 32); a3 += __shfl_down(a3, 32);
    b0 += __shfl_down(b0, 32); b1 += __shfl_down(b1, 32);
    b2 += __shfl_down(b2, 32); b3 += __shfl_down(b3, 32);
    a0 += __shfl_down(a0, 16); a1 += __shfl_down(a1, 16);
    a2 += __shfl_down(a2, 16); a3 += __shfl_down(a3, 16);
    b0 += __shfl_down(b0, 16); b1 += __shfl_down(b1, 16);
    b2 += __shfl_down(b2, 16); b3 += __shfl_down(b3, 16);

    if (lane < 16) {
        float4 bv = *(const float4*)(bias + c4);
        float vA0 = fmaxf(a0 + bv.x, 0.f), vA1 = fmaxf(a1 + bv.y, 0.f);
        float vA2 = fmaxf(a2 + bv.z, 0.f), vA3 = fmaxf(a3 + bv.w, 0.f);
        float vB0 = fmaxf(b0 + bv.x, 0.f), vB1 = fmaxf(b1 + bv.y, 0.f);
        float vB2 = fmaxf(b2 + bv.z, 0.f), vB3 = fmaxf(b3 + bv.w, 0.f);
        *(ushort4*)(out + (size_t)n0 * 64 + c4) =
            make_ushort4(f2bf(vA0), f2bf(vA1), f2bf(vA2), f2bf(vA3));
        *(ushort4*)(out + (size_t)n1 * 64 + c4) =
            make_ushort4(f2bf(vB0), f2bf(vB1), f2bf(vB2), f2bf(vB3));
    }
}

// ---------------------------------------------------------------------------
// Gather layer 2 + W2 (linearity; R13 numerics PASS). Differences vs R13:
// coalesced float4 row stores via f32 strip (R13's scattered scalar f32
// stores caused +70MB write-allocate fetch -- the entire fusion tax).
// Wave-private strips + wave_barrier only; single block barrier at START
// (W2 staging) before any variable-length work.
// ---------------------------------------------------------------------------
__global__ __launch_bounds__(256) void k_gather2mm(
    const ushort_t* __restrict__ H, const int2* __restrict__ recs,
    const int2* __restrict__ nodeinfo, const float* __restrict__ bias2,
    const float* __restrict__ W2, float* __restrict__ out)
{
    __shared__ ushort_t sW[64 * 72];       // W2^T staged bf16 (gemm2 layout)
    __shared__ ushort_t strip[4][128];     // per-wave 2x64 bf16 agg rows
    __shared__ float    fstrip[4][128];    // per-wave 2x64 f32 result rows

    const int tid  = threadIdx.x;
    const int wid  = tid >> 6;
    const int lane = tid & 63;
    const int n0   = (blockIdx.x * 4 + wid) * 2;   // grid = N/8 exactly
    const int n1   = n0 + 1;

    // stage W2 (64x64 f32) -> sW[n][k] bf16 (n-major, stride 72)
    for (int i = tid; i < 64 * 16; i += 256) {
        int k = i >> 4, n4 = (i & 15) * 4;
        float4 v = *(const float4*)(W2 + (size_t)k * 64 + n4);
        sW[(n4 + 0) * 72 + k] = f2bf(v.x);
        sW[(n4 + 1) * 72 + k] = f2bf(v.y);
        sW[(n4 + 2) * 72 + k] = f2bf(v.z);
        sW[(n4 + 3) * 72 + k] = f2bf(v.w);
    }
    __syncthreads();                       // ONLY block barrier (at start)

    const int2 niA = nodeinfo[n0];
    const int2 niB = nodeinfo[n1];
    int baseA = niA.x; const int endA = niA.x + niA.y;
    int baseB = niB.x; const int endB = niB.x + niB.y;

    const int g  = lane >> 4;
    const int c4 = (lane & 15) * 4;

    float a0 = 0.f, a1 = 0.f, a2 = 0.f, a3 = 0.f;
    float b0 = 0.f, b1 = 0.f, b2 = 0.f, b3 = 0.f;

    while (baseA < endA || baseB < endB) {
        int mA = endA - baseA; if (mA > 64) mA = 64;
        int mB = endB - baseB; if (mB > 64) mB = 64;
        int2 rA = (mA > 0) ? recs[baseA + (lane < mA ? lane : mA - 1)]
                           : make_int2(0, 0);
        int2 rB = (mB > 0) ? recs[baseB + (lane < mB ? lane : mB - 1)]
                           : make_int2(0, 0);
        float wAf = __int_as_float(rA.y);
        float wBf = __int_as_float(rB.y);
        int mm = mA > mB ? mA : mB;
        #pragma unroll 4
        for (int jj = 0; jj < mm; jj += 4) {
            int idx = jj + g;
            int   sA_ = __shfl(rA.x, idx);
            float wA  = __shfl(wAf, idx);
            int   sB_ = __shfl(rB.x, idx);
            float wB  = __shfl(wBf, idx);
            if (idx >= mA) wA = 0.f;
            if (idx >= mB) wB = 0.f;
            ushort4 hA = *(const ushort4*)(H + (size_t)sA_ * 64 + c4);
            ushort4 hB = *(const ushort4*)(H + (size_t)sB_ * 64 + c4);
            a0 = fmaf(wA, bf2f(hA.x), a0);
            a1 = fmaf(wA, bf2f(hA.y), a1);
            a2 = fmaf(wA, bf2f(hA.z), a2);
            a3 = fmaf(wA, bf2f(hA.w), a3);
            b0 = fmaf(wB, bf2f(hB.x), b0);
            b1 = fmaf(wB, bf2f(hB.y), b1);
            b2 = fmaf(wB, bf2f(hB.z), b2);
            b3 = fmaf(wB, bf2f(hB.w), b3);
        }
        baseA += 64;
        baseB += 64;
    }
    a0 += __shfl_down(a0, 32); a1 += __shfl_down(a1, 32);
    a2 += __shfl_down(a2, 32); a3 += __shfl_down(a3, 32);
    b0 += __shfl_down(b0, 32); b1 += __shfl_down(b1, 32);
    b2 += __shfl_down(b2, 32); b3 += __shfl_down(b3, 32);
    a0 += __shfl_down(a0, 16); a1 += __shfl_down(a1, 16);
    a2 += __shfl_down(a2, 16); a3 += __shfl_down(a3, 16);
    b0 += __shfl_down(b0, 16); b1 += __shfl_down(b1, 16);
    b2 += __shfl_down(b2, 16); b3 += __shfl_down(b3, 16);

    // aggregated rows -> wave-private strip (bf16; R13-verified numerics)
    if (lane < 16) {
        *(ushort4*)(&strip[wid][0 * 64 + c4]) =
            make_ushort4(f2bf(a0), f2bf(a1), f2bf(a2), f2bf(a3));
        *(ushort4*)(&strip[wid][1 * 64 + c4]) =
            make_ushort4(f2bf(b0), f2bf(b1), f2bf(b2), f2bf(b3));
    }
    __builtin_amdgcn_wave_barrier();       // same-wave LDS ordering

    // (agg)@W2 via MFMA: A rows 0,1 valid (row = m&1); rows 2..15 garbage
    const int m = lane & 15, quad = lane >> 4;
    const ushort_t* sp = strip[wid];
    floatx4 acc2[4] = {};
    #pragma unroll
    for (int ks = 0; ks < 2; ++ks) {
        bf16x8 a = *(const bf16x8*)(sp + (m & 1) * 64 + ks * 32 + quad * 8);
        #pragma unroll
        for (int nt = 0; nt < 4; ++nt) {
            bf16x8 bfr = *(const bf16x8*)(sW + (nt * 16 + m) * 72 + ks * 32 + quad * 8);
            acc2[nt] = __builtin_amdgcn_mfma_f32_16x16x32_bf16(a, bfr, acc2[nt], 0, 0, 0);
        }
    }
    // C rows 0,1 live in quad==0, regs 0,1; col = nt*16+m -> f32 strip
    if (quad == 0) {
        #pragma unroll
        for (int nt = 0; nt < 4; ++nt) {
            fstrip[wid][0 * 64 + nt * 16 + m] = acc2[nt][0];
            fstrip[wid][1 * 64 + nt * 16 + m] = acc2[nt][1];
        }
    }
    __builtin_amdgcn_wave_barrier();

    // coalesced row stores: 32 lanes x float4 = 2 full rows (256B each)
    if (lane < 32) {
        int rr  = lane >> 4;               // 0 -> n0, 1 -> n1
        int mm2 = (lane & 15) * 4;
        float4 v  = *(const float4*)(&fstrip[wid][rr * 64 + mm2]);
        float4 bv = *(const float4*)(bias2 + mm2);
        *(float4*)(out + (size_t)(n0 + rr) * 64 + mm2) =
            make_float4(v.x + bv.x, v.y + bv.y, v.z + bv.z, v.w + bv.w);
    }
}

// ---------------------------------------------------------------------------
extern "C" void kernel_launch(void* const* d_in, const int* in_sizes, int n_in,
                              void* d_out, int out_size, void* d_ws, size_t ws_size,
                              hipStream_t stream) {
    const float* x   = (const float*)d_in[0];
    const int*   ei  = (const int*)  d_in[1];
    const float* ew  = (const float*)d_in[2];
    const float* w1  = (const float*)d_in[3];
    const float* b1  = (const float*)d_in[4];
    const float* w2  = (const float*)d_in[5];
    const float* b2  = (const float*)d_in[6];
    float* out = (float*)d_out;

    const int N = N_NODES, E = N_EDGES;
    const int* src = ei;
    const int* dst = ei + E;

    char* p = (char*)d_ws;
    ushort_t* bufA   = (ushort_t*)p;  p += (size_t)N_NODES * 64 * 2;   // 12.8MB: h1
    int2*     recs2  = (int2*)p;      p += (size_t)NB1 * CAP1 * 8;     // 14.7MB: exact CSR
    // recs1 (pass-1 output) aliases bufB: recs1 dead after k_pass2, which
    // completes before k_gather1 writes bufB (stream-ordered).
    int2*     recs1  = (int2*)p;
    ushort_t* bufB   = (ushort_t*)p;  p += (size_t)NB1 * CAP1 * 8;     // 14.7MB: h1'
    int*      gcur   = (int*)p;       p += 2048;
    int2*     ninfo  = (int2*)p;      p += (size_t)N_NODES * 8;        // 0.8MB

    // ---- sort pass1 + GEMM1 fused (independent; overlap on CU array)
    k_init <<<1, 512, 0, stream>>>(gcur);
    k_p1g1 <<<NT1 + GB1, 512, 0, stream>>>(src, dst, ew, gcur, recs1, E,
                                           x, w1, bufA, N);
    k_pass2<<<NB1, 1024, 0, stream>>>(recs1, gcur, recs2, ninfo, N);

    // ---- layer 1 aggregate (h1' -> bufB)
    k_gather1<<<N / 8, 256, 0, stream>>>(bufA, recs2, ninfo, b1, bufB);

    // ---- layer 2 aggregate + in-wave W2 transform (gemm2 eliminated)
    k_gather2mm<<<N / 8, 256, 0, stream>>>(bufB, recs2, ninfo, b2, w2, out);
}

// Round 8
// 233.658 us; speedup vs baseline: 2.3856x; 1.0409x over previous
//
#include <hip/hip_runtime.h>
#include <hip/hip_bf16.h>

// GCN 2-layer: h1' = relu(S·(x@w1) + b1); out = S·(h1'@w2) + b2
// Single-pass bucket multisplit (global cursor reservation) -> exact CSR by
// dst; gather = 2 nodes/wave, 16 lanes x ushort4/edge, 64-wide rec preload
// + shfl broadcast. bf16 MFMA GEMMs. N=100000, E=1600000, IN=128, HID=64.
//
// Perf journal:
//  R1 2862; R2 633; R3 466; R4 1587 REG; R5 326; R6 262; R7 276 REG
//  R8 246.8; R9 232.6 BEST (fused p1+gemm1, pass2@1024, unroll4)
//  R10 235.6 REG occupancy play; R11 247.8 REG fusion tax #1;
//  R12 255.1 REG issue-phase gather neutral + reg-staged p1 loss;
//  R13 245.3 REG fusion tax #2; R14 557.4 REG cooperative TLP strangle;
//  R15 243.2 REG fusion tax #3 -- W2 re-staging (FETCH +70MB) intrinsic.
//     FUSION INTO GATHER DISPROVEN x3. Gather = ~26us VALU-issue + stalls.
//  R16 (this): exact R9 + three orthogonal cuts, no structure change:
//     (a) gather masks hoisted to per-round weight zeroing (-4 ops/iter);
//     (b) 32-bit H addressing, SGPR base + voffset (-6 ops/iter);
//     (c) k_init deleted (hipMemsetAsync + relative reservation cursor).

#define N_NODES 100000
#define N_EDGES 1600000
#define NB1     391     // coarse buckets of 256 dst nodes (dst>>8)
#define T1      4096    // pass-1 tile (edges per block)
#define NT1     391     // ceil(E/T1)
#define CAP1    4706    // per-bucket slack: mean 4092 + 9.6 sigma
#define GB1     782     // fused-kernel gemm blocks: ceil(N/128)

typedef unsigned short ushort_t;
typedef unsigned int uint_t;
typedef __attribute__((ext_vector_type(8))) short bf16x8;
typedef __attribute__((ext_vector_type(4))) float floatx4;
typedef __attribute__((ext_vector_type(8))) ushort_t ushort8v;

static __device__ __forceinline__ float bf2f(ushort_t h) {
    return __uint_as_float(((uint_t)h) << 16);
}
static __device__ __forceinline__ ushort_t f2bf(float f) {
    uint_t u = __float_as_uint(f);
    u = (u + 0x7FFF + ((u >> 16) & 1)) >> 16;   // RNE
    return (ushort_t)u;
}

// ---------------------------------------------------------------------------
// FUSED: blocks [0,NT1) run sort pass 1; blocks [NT1,NT1+GB1) run GEMM1.
// Data-independent roles overlap on the CU array. (R9 bodies; only the
// reservation is relative now: gcursor zeroed by hipMemsetAsync.)
// ---------------------------------------------------------------------------
__global__ __launch_bounds__(512) void k_p1g1(
    const int* __restrict__ src, const int* __restrict__ dst,
    const float* __restrict__ ew, int* __restrict__ gcursor,
    int2* __restrict__ recs1, int E,
    const float* __restrict__ X, const float* __restrict__ W,
    ushort_t* __restrict__ Y, int N)
{
    __shared__ __align__(16) char smem[52224];
    const int tid = threadIdx.x;

    if (blockIdx.x < NT1) {
        // ---------------- sort pass 1 ----------------
        int* cnt     = (int*)smem;             // [NB1]
        int* start   = cnt + NB1;
        int* cursor  = start + NB1;
        int* gb      = cursor + NB1;
        int* s       = (int*)(smem + 6256);    // [512]
        int2* stg    = (int2*)(smem + 8304);   // [T1]
        ushort_t* sb = (ushort_t*)(smem + 41072); // [T1]
        const int t = tid, b = blockIdx.x;

        if (t < NB1) cnt[t] = 0;
        __syncthreads();
        const int e0 = b * T1;
        const int e1 = min(E, e0 + T1);
        for (int e = e0 + t; e < e1; e += 512)
            atomicAdd(&cnt[dst[e] >> 8], 1);
        __syncthreads();
        const int v = (t < NB1) ? cnt[t] : 0;
        s[t] = v;
        #pragma unroll
        for (int off = 1; off < 512; off <<= 1) {
            __syncthreads();
            int a = (t >= off) ? s[t - off] : 0;
            __syncthreads();
            s[t] += a;
        }
        __syncthreads();
        if (t < NB1) {
            int st = s[t] - v;
            start[t]  = st;
            cursor[t] = st;
            // relative reservation (gcursor starts at 0 via memset);
            // absolute base folded in here:
            gb[t] = t * CAP1 + atomicAdd(&gcursor[t], v);
        }
        __syncthreads();
        for (int e = e0 + t; e < e1; e += 512) {
            int d  = dst[e];
            int bk = d >> 8;
            int p  = atomicAdd(&cursor[bk], 1);
            int2 r;
            r.x = ((d & 255) << 17) | src[e];
            r.y = __float_as_int(ew[e]);
            stg[p] = r;
            sb[p]  = (ushort_t)bk;
        }
        __syncthreads();
        const int n = e1 - e0;
        for (int i = t; i < n; i += 512) {
            int bk = sb[i];
            recs1[gb[bk] + (i - start[bk])] = stg[i];
        }
    } else {
        // ---------------- GEMM1, 128 rows ----------------
        ushort_t* sA = (ushort_t*)smem;             // 128 x 136
        ushort_t* sB = (ushort_t*)(smem + 34816);   // 64 x 136 (transposed)
        const int b    = blockIdx.x - NT1;
        const int row0 = b * 128;

        for (int i = tid; i < 128 * 32; i += 512) {    // A: 128 rows x 32 f4
            int r = i >> 5, c4 = (i & 31) * 4;
            int rg = row0 + r; if (rg > N - 1) rg = N - 1;
            float4 v = *(const float4*)(X + (size_t)rg * 128 + c4);
            ushort4 pk = make_ushort4(f2bf(v.x), f2bf(v.y), f2bf(v.z), f2bf(v.w));
            *(ushort4*)(sA + r * 136 + c4) = pk;
        }
        for (int i = tid; i < 128 * 16; i += 512) {    // B: 128 rows x 16 f4
            int k = i >> 4, n4 = (i & 15) * 4;
            float4 v = *(const float4*)(W + (size_t)k * 64 + n4);
            sB[(n4 + 0) * 136 + k] = f2bf(v.x);
            sB[(n4 + 1) * 136 + k] = f2bf(v.y);
            sB[(n4 + 2) * 136 + k] = f2bf(v.z);
            sB[(n4 + 3) * 136 + k] = f2bf(v.w);
        }
        __syncthreads();

        const int wid = tid >> 6, lane = tid & 63;     // wid 0..7 -> 128 rows
        const int m = lane & 15, quad = lane >> 4;
        floatx4 acc[4] = {};

        #pragma unroll
        for (int ks = 0; ks < 4; ++ks) {
            bf16x8 a = *(const bf16x8*)(sA + (wid * 16 + m) * 136 + ks * 32 + quad * 8);
            #pragma unroll
            for (int nt = 0; nt < 4; ++nt) {
                bf16x8 bfr = *(const bf16x8*)(sB + (nt * 16 + m) * 136 + ks * 32 + quad * 8);
                acc[nt] = __builtin_amdgcn_mfma_f32_16x16x32_bf16(a, bfr, acc[nt], 0, 0, 0);
            }
        }
        __syncthreads();                    // all sA reads done
        #pragma unroll
        for (int nt = 0; nt < 4; ++nt)
            #pragma unroll
            for (int r = 0; r < 4; ++r)
                sA[(wid * 16 + quad * 4 + r) * 72 + nt * 16 + m] = f2bf(acc[nt][r]);
        __syncthreads();
        for (int i = tid; i < 128 * 8; i += 512) {     // coalesced C store
            int rr = i >> 3, c8 = (i & 7) * 8;
            int rg = row0 + rr;
            if (rg < N)
                *(ushort8v*)(Y + (size_t)rg * 64 + c8) =
                    *(const ushort8v*)(sA + rr * 72 + c8);
        }
    }
}

// ---------------------------------------------------------------------------
// Pass 2 (R9 verbatim; hi now lo + relative count): one block per coarse
// bucket -> exact per-node CSR. ninfo[n]={start,cnt}.
// ---------------------------------------------------------------------------
__global__ __launch_bounds__(1024) void k_pass2(
    const int2* __restrict__ recs1, const int* __restrict__ gcursor,
    int2* __restrict__ recs2, int2* __restrict__ nodeinfo, int N)
{
    __shared__ int cnt[256];
    __shared__ int s[256];
    __shared__ int cursor[256];
    const int t = threadIdx.x, b = blockIdx.x;
    const int lo = b * CAP1;
    const int hi = lo + gcursor[b];

    if (t < 256) cnt[t] = 0;
    __syncthreads();
    for (int j = lo + t; j < hi; j += 1024)
        atomicAdd(&cnt[((uint_t)recs1[j].x) >> 17], 1);
    __syncthreads();
    const int v = (t < 256) ? cnt[t] : 0;
    if (t < 256) s[t] = v;
    #pragma unroll
    for (int off = 1; off < 256; off <<= 1) {
        __syncthreads();
        int a = (t >= off && t < 256) ? s[t - off] : 0;
        __syncthreads();
        if (t < 256) s[t] += a;
    }
    __syncthreads();
    if (t < 256) {
        const int stl = s[t] - v;
        cursor[t] = stl;
        const int ng = b * 256 + t;
        if (ng < N) {
            int2 ni; ni.x = lo + stl; ni.y = v;
            nodeinfo[ng] = ni;
        }
    }
    __syncthreads();
    for (int j = lo + t; j < hi; j += 1024) {
        int2 r = recs1[j];
        int dl = ((uint_t)r.x) >> 17;
        int p  = atomicAdd(&cursor[dl], 1);
        int2 o;
        o.x = r.x & 0x1FFFF;
        o.y = r.y;
        recs2[lo + p] = o;
    }
}

// ---------------------------------------------------------------------------
// MFMA GEMM2 (R9 verbatim): Y[bf16, N x 64] = X[bf16, N x 64] @ bf16(W)
// ---------------------------------------------------------------------------
__global__ __launch_bounds__(256) void k_gemm2(
    const ushort_t* __restrict__ X, const float* __restrict__ W,
    ushort_t* __restrict__ Y, int N)
{
    __shared__ ushort_t sA[64 * 72];    // 9216 B; reused for C stage
    __shared__ ushort_t sB[64 * 72];
    const int tid  = threadIdx.x;
    const int row0 = blockIdx.x * 64;

    for (int i = tid; i < 64 * 16; i += 256) {         // A: 64 rows x 16 us4
        int r = i >> 4, c4 = (i & 15) * 4;
        int rg = row0 + r; if (rg > N - 1) rg = N - 1;
        *(ushort4*)(sA + r * 72 + c4) =
            *(const ushort4*)(X + (size_t)rg * 64 + c4);
    }
    for (int i = tid; i < 64 * 16; i += 256) {         // B: 64 rows x 16 f4
        int k = i >> 4, n4 = (i & 15) * 4;
        float4 v = *(const float4*)(W + (size_t)k * 64 + n4);
        sB[(n4 + 0) * 72 + k] = f2bf(v.x);
        sB[(n4 + 1) * 72 + k] = f2bf(v.y);
        sB[(n4 + 2) * 72 + k] = f2bf(v.z);
        sB[(n4 + 3) * 72 + k] = f2bf(v.w);
    }
    __syncthreads();

    const int wid = tid >> 6, lane = tid & 63;
    const int m = lane & 15, quad = lane >> 4;
    floatx4 acc[4] = {};

    #pragma unroll
    for (int ks = 0; ks < 2; ++ks) {
        bf16x8 a = *(const bf16x8*)(sA + (wid * 16 + m) * 72 + ks * 32 + quad * 8);
        #pragma unroll
        for (int nt = 0; nt < 4; ++nt) {
            bf16x8 bfr = *(const bf16x8*)(sB + (nt * 16 + m) * 72 + ks * 32 + quad * 8);
            acc[nt] = __builtin_amdgcn_mfma_f32_16x16x32_bf16(a, bfr, acc[nt], 0, 0, 0);
        }
    }
    __syncthreads();
    #pragma unroll
    for (int nt = 0; nt < 4; ++nt)
        #pragma unroll
        for (int r = 0; r < 4; ++r)
            sA[(wid * 16 + quad * 4 + r) * 72 + nt * 16 + m] = f2bf(acc[nt][r]);
    __syncthreads();
    for (int i = tid; i < 64 * 8; i += 256) {
        int rr = i >> 3, c8 = (i & 7) * 8;
        int rg = row0 + rr;
        if (rg < N)
            *(ushort8v*)(Y + (size_t)rg * 64 + c8) =
                *(const ushort8v*)(sA + rr * 72 + c8);
    }
}

// ---------------------------------------------------------------------------
// Gather-reduce (R9 structure): TWO nodes per wave; 64-rec preload + shfl
// broadcast; 16 lanes x ushort4/edge; unroll 4. R16 deltas:
//  - per-round weight zeroing in the PRELOAD (lane >= m -> w = 0) replaces
//    per-iteration idx>=m masks (exact same numerics: fmaf(0,h,acc)==acc);
//  - 32-bit H offsets ((src<<6)|c4, src < 2^17) -> SGPR-base + voffset.
// ---------------------------------------------------------------------------
template<bool RELU, bool OUT_BF16>
__global__ __launch_bounds__(256) void k_gather(
    const ushort_t* __restrict__ H, const int2* __restrict__ recs,
    const int2* __restrict__ nodeinfo, const float* __restrict__ bias,
    void* __restrict__ out)
{
    const int wid  = threadIdx.x >> 6;
    const int lane = threadIdx.x & 63;
    const int n0   = (blockIdx.x * 4 + wid) * 2;   // grid = N/8 exactly
    const int n1   = n0 + 1;

    const int2 niA = nodeinfo[n0];
    const int2 niB = nodeinfo[n1];
    int baseA = niA.x; const int endA = niA.x + niA.y;
    int baseB = niB.x; const int endB = niB.x + niB.y;

    const int g  = lane >> 4;           // edge slot in round
    const int c4 = (lane & 15) * 4;     // channel base

    float a0 = 0.f, a1 = 0.f, a2 = 0.f, a3 = 0.f;
    float b0 = 0.f, b1 = 0.f, b2 = 0.f, b3 = 0.f;

    while (baseA < endA || baseB < endB) {
        int mA = endA - baseA; if (mA > 64) mA = 64;
        int mB = endB - baseB; if (mB > 64) mB = 64;
        int2 rA = (mA > 0) ? recs[baseA + (lane < mA ? lane : mA - 1)]
                           : make_int2(0, 0);
        int2 rB = (mB > 0) ? recs[baseB + (lane < mB ? lane : mB - 1)]
                           : make_int2(0, 0);
        // hoisted masking: zero the weight ONCE per round; shfl then
        // broadcasts zero for exhausted slots (clamped src load harmless)
        float wAf = (lane < mA) ? __int_as_float(rA.y) : 0.f;
        float wBf = (lane < mB) ? __int_as_float(rB.y) : 0.f;
        int mm = mA > mB ? mA : mB;
        #pragma unroll 4
        for (int jj = 0; jj < mm; jj += 4) {
            int idx = jj + g;
            int   sA = __shfl(rA.x, idx);
            float wA = __shfl(wAf, idx);
            int   sB = __shfl(rB.x, idx);
            float wB = __shfl(wBf, idx);
            ushort4 hA = *(const ushort4*)(H + (uint_t)((sA << 6) | c4));
            ushort4 hB = *(const ushort4*)(H + (uint_t)((sB << 6) | c4));
            a0 = fmaf(wA, bf2f(hA.x), a0);
            a1 = fmaf(wA, bf2f(hA.y), a1);
            a2 = fmaf(wA, bf2f(hA.z), a2);
            a3 = fmaf(wA, bf2f(hA.w), a3);
            b0 = fmaf(wB, bf2f(hB.x), b0);
            b1 = fmaf(wB, bf2f(hB.y), b1);
            b2 = fmaf(wB, bf2f(hB.z), b2);
            b3 = fmaf(wB, bf2f(hB.w), b3);
        }
        baseA += 64;
        baseB += 64;
    }
    // reduce across the 4 groups (lanes l, l+16, l+32, l+48)
    a0 += __shfl_down(a0, 32); a1 += __shfl_down(a1, 32);
    a2 += __shfl_down(a2, 32); a3 += __shfl_down(a3, 32);
    b0 += __shfl_down(b0, 32); b1 += __shfl_down(b1, 32);
    b2 += __shfl_down(b2, 32); b3 += __shfl_down(b3, 32);
    a0 += __shfl_down(a0, 16); a1 += __shfl_down(a1, 16);
    a2 += __shfl_down(a2, 16); a3 += __shfl_down(a3, 16);
    b0 += __shfl_down(b0, 16); b1 += __shfl_down(b1, 16);
    b2 += __shfl_down(b2, 16); b3 += __shfl_down(b3, 16);

    if (lane < 16) {
        float4 bv = *(const float4*)(bias + c4);
        float vA0 = a0 + bv.x, vA1 = a1 + bv.y, vA2 = a2 + bv.z, vA3 = a3 + bv.w;
        float vB0 = b0 + bv.x, vB1 = b1 + bv.y, vB2 = b2 + bv.z, vB3 = b3 + bv.w;
        if (RELU) {
            vA0 = fmaxf(vA0, 0.f); vA1 = fmaxf(vA1, 0.f);
            vA2 = fmaxf(vA2, 0.f); vA3 = fmaxf(vA3, 0.f);
            vB0 = fmaxf(vB0, 0.f); vB1 = fmaxf(vB1, 0.f);
            vB2 = fmaxf(vB2, 0.f); vB3 = fmaxf(vB3, 0.f);
        }
        if (OUT_BF16) {
            *(ushort4*)((ushort_t*)out + (size_t)n0 * 64 + c4) =
                make_ushort4(f2bf(vA0), f2bf(vA1), f2bf(vA2), f2bf(vA3));
            *(ushort4*)((ushort_t*)out + (size_t)n1 * 64 + c4) =
                make_ushort4(f2bf(vB0), f2bf(vB1), f2bf(vB2), f2bf(vB3));
        } else {
            *(float4*)((float*)out + (size_t)n0 * 64 + c4) =
                make_float4(vA0, vA1, vA2, vA3);
            *(float4*)((float*)out + (size_t)n1 * 64 + c4) =
                make_float4(vB0, vB1, vB2, vB3);
        }
    }
}

// ---------------------------------------------------------------------------
extern "C" void kernel_launch(void* const* d_in, const int* in_sizes, int n_in,
                              void* d_out, int out_size, void* d_ws, size_t ws_size,
                              hipStream_t stream) {
    const float* x   = (const float*)d_in[0];
    const int*   ei  = (const int*)  d_in[1];
    const float* ew  = (const float*)d_in[2];
    const float* w1  = (const float*)d_in[3];
    const float* b1  = (const float*)d_in[4];
    const float* w2  = (const float*)d_in[5];
    const float* b2  = (const float*)d_in[6];
    float* out = (float*)d_out;

    const int N = N_NODES, E = N_EDGES;
    const int* src = ei;
    const int* dst = ei + E;

    char* p = (char*)d_ws;
    ushort_t* bufA   = (ushort_t*)p;  p += (size_t)N_NODES * 64 * 2;   // 12.8MB: h1 / h2
    int2*     recs2  = (int2*)p;      p += (size_t)NB1 * CAP1 * 8;     // 14.7MB: exact CSR
    // recs1 (pass-1 output) aliases bufB: recs1 dead after k_pass2, which
    // completes before k_gather writes bufB (stream-ordered).
    int2*     recs1  = (int2*)p;
    ushort_t* bufB   = (ushort_t*)p;  p += (size_t)NB1 * CAP1 * 8;     // 14.7MB
    int*      gcur   = (int*)p;       p += 2048;
    int2*     ninfo  = (int2*)p;      p += (size_t)N_NODES * 8;        // 0.8MB

    // ---- cursor zero (replaces k_init; reservation is relative now)
    hipMemsetAsync(gcur, 0, 2048, stream);

    // ---- sort pass1 + GEMM1 fused (independent; overlap on CU array)
    k_p1g1 <<<NT1 + GB1, 512, 0, stream>>>(src, dst, ew, gcur, recs1, E,
                                           x, w1, bufA, N);
    k_pass2<<<NB1, 1024, 0, stream>>>(recs1, gcur, recs2, ninfo, N);

    // ---- layer 1
    k_gather<true, true><<<N / 8, 256, 0, stream>>>(bufA, recs2, ninfo, b1, bufB);

    // ---- layer 2
    k_gemm2<<<(N + 63) / 64, 256, 0, stream>>>(bufB, w2, bufA, N);
    k_gather<false, false><<<N / 8, 256, 0, stream>>>(bufA, recs2, ninfo, b2, out);
}